// Round 2
// baseline (24.219 us; speedup 1.0000x reference)
//
#include <hip/hip_runtime.h>

#define NQ 4
#define DIMQ 16
#define NLAY 8
#define NOUT 4
#define NPAIR 136   // 16*17/2 upper-triangle entries

// ---------------------------------------------------------------------------
// Setup kernel (1 block, 256 threads): builds three symmetric-folded matrices
//   A_m = 0.5 * ( sum_{k<4} ent0[k]^2 * U_k^T D_m U_k + (sum_{k>=4} ent0[k]^2) * D_m )
// packed as upper-triangle (t<=u), off-diagonal entries pre-doubled, so
//   out[b][m] = 0.5 + sum_{t<=u} Apack[m][idx(t,u)] * enc[t]*enc[u].
// ---------------------------------------------------------------------------
__global__ __launch_bounds__(256) void qnn_setup(const float* __restrict__ alpha,
                                                 const float* __restrict__ thetas,
                                                 float* __restrict__ A_out) {
    __shared__ float U[NOUT][DIMQ][DIMQ];  // U[k][row][col]
    __shared__ float w[5];                 // w[0..3] = ent0[k]^2, w[4] = sum_{k>=4}
    const int tid = threadIdx.x;

    // Threads 0..63: simulate column `col` of unitary `k` (state-vector, 16 amps)
    if (tid < 64) {
        const int k = tid >> 4, col = tid & 15;
        float st[16];
        #pragma unroll
        for (int i = 0; i < 16; ++i) st[i] = (i == col) ? 1.0f : 0.0f;
        const float* th = thetas + k * (NLAY * NQ);
        for (int l = 0; l < NLAY; ++l) {
            // RY on each qubit q (qubit 0 = MSB -> bit position 3-q)
            for (int q = 0; q < NQ; ++q) {
                const float t = th[l * NQ + q] * 0.5f;
                const float c = cosf(t), s = sinf(t);
                const int pb = 1 << (3 - q);
                #pragma unroll
                for (int i0 = 0; i0 < 16; ++i0) {
                    if (i0 & pb) continue;
                    const int i1 = i0 | pb;
                    const float a0 = st[i0], a1 = st[i1];
                    st[i0] = c * a0 - s * a1;   // RY = [[c,-s],[s,c]]
                    st[i1] = s * a0 + c * a1;
                }
            }
            // Entangler: CNOT(0,1), CNOT(1,2), CNOT(2,3) in that order.
            for (int q = 0; q < NQ - 1; ++q) {
                const int cb = 1 << (3 - q), tb = 1 << (2 - q);
                #pragma unroll
                for (int i = 0; i < 16; ++i) {
                    if ((i & cb) && !(i & tb)) {
                        const int j = i | tb;
                        const float tmp = st[i]; st[i] = st[j]; st[j] = tmp;
                    }
                }
            }
        }
        #pragma unroll
        for (int r = 0; r < 16; ++r) U[k][r][col] = st[r];
    }

    // Thread 64: ancilla tree state ent0 and the weights.
    if (tid == 64) {
        float e[8];
        #pragma unroll
        for (int i = 0; i < 8; ++i) e[i] = (i == 0) ? 1.0f : 0.0f;
        int idx = 0;
        for (int l = 0; l < 3; ++l) {
            const int p = 2 - l, pb = 1 << p;
            #pragma unroll
            for (int i0 = 0; i0 < 8; ++i0) {
                if (i0 & pb) continue;
                const int i1 = i0 | pb;
                const int blk = i0 >> (p + 1);
                const float t = alpha[idx + blk] * 0.5f;
                const float c = cosf(t), s = sinf(t);
                const float a0 = e[i0], a1 = e[i1];
                e[i0] = c * a0 - s * a1;
                e[i1] = s * a0 + c * a1;
            }
            idx += (1 << l);
        }
        for (int k = 0; k < 4; ++k) w[k] = e[k] * e[k];
        w[4] = e[4]*e[4] + e[5]*e[5] + e[6]*e[6] + e[7]*e[7];
    }

    __syncthreads();

    // 408 packed entries: e = m*NPAIR + triangular idx(t,u), t<=u.
    for (int e = tid; e < 3 * NPAIR; e += 256) {
        const int m = e / NPAIR;
        int r = e - m * NPAIR;
        int t = 0;
        while (r >= 16 - t) { r -= 16 - t; ++t; }
        const int u = t + r;

        const int bit = 3 - m;  // e3 -> bit3, e4 -> bit2, e5 -> bit1
        float acc = (t == u) ? (((t >> bit) & 1) ? -w[4] : w[4]) : 0.0f;
        for (int k = 0; k < NOUT; ++k) {
            float sk = 0.0f;
            #pragma unroll
            for (int rr = 0; rr < 16; ++rr) {
                const float sg = ((rr >> bit) & 1) ? -1.0f : 1.0f;
                sk = fmaf(U[k][rr][t] * sg, U[k][rr][u], sk);
            }
            acc = fmaf(w[k], sk, acc);
        }
        const float scale = (t == u) ? 0.5f : 1.0f;  // 0.5 output fold, x2 off-diag
        A_out[e] = scale * acc;
    }
}

// ---------------------------------------------------------------------------
// Main kernel: one thread per sample. A read via uniform (scalarized) loads.
// ---------------------------------------------------------------------------
__global__ __launch_bounds__(256) void qnn_main(const float4* __restrict__ x,
                                                const float* __restrict__ A,
                                                float* __restrict__ out,
                                                int batch) {
    const int b = blockIdx.x * 256 + threadIdx.x;
    if (b >= batch) return;

    const float4 xv = x[b];
    float c0, s0, c1, s1, c2, s2, c3, s3;
    sincospif(xv.x, &s0, &c0);
    sincospif(xv.y, &s1, &c1);
    sincospif(xv.z, &s2, &c2);
    sincospif(xv.w, &s3, &c3);

    // enc[t] = (bit3? s0:c0)(bit2? s1:c1)(bit1? s2:c2)(bit0? s3:c3)
    float f01[4], f23[4];
    f01[0] = c0 * c1; f01[1] = c0 * s1; f01[2] = s0 * c1; f01[3] = s0 * s1;
    f23[0] = c2 * c3; f23[1] = c2 * s3; f23[2] = s2 * c3; f23[3] = s2 * s3;
    float enc[16];
    #pragma unroll
    for (int t = 0; t < 16; ++t) enc[t] = f01[t >> 2] * f23[t & 3];

    float e0 = 0.5f, e1 = 0.5f, e2 = 0.5f;
    int idx = 0;
    #pragma unroll
    for (int t = 0; t < 16; ++t) {
        #pragma unroll
        for (int u = t; u < 16; ++u) {
            const float p = enc[t] * enc[u];
            e0 = fmaf(A[idx],              p, e0);
            e1 = fmaf(A[NPAIR + idx],      p, e1);
            e2 = fmaf(A[2 * NPAIR + idx],  p, e2);
            ++idx;
        }
    }

    out[b * 3 + 0] = e0;
    out[b * 3 + 1] = e1;
    out[b * 3 + 2] = e2;
}

extern "C" void kernel_launch(void* const* d_in, const int* in_sizes, int n_in,
                              void* d_out, int out_size, void* d_ws, size_t ws_size,
                              hipStream_t stream) {
    const float* x      = (const float*)d_in[0];   // (131072, 4) f32
    const float* alpha  = (const float*)d_in[1];   // (7,) f32
    const float* thetas = (const float*)d_in[2];   // (4, 32) f32
    float* A = (float*)d_ws;                       // 3*136 floats scratch

    qnn_setup<<<1, 256, 0, stream>>>(alpha, thetas, A);

    const int batch = in_sizes[0] / 4;
    const int blocks = (batch + 255) / 256;
    qnn_main<<<blocks, 256, 0, stream>>>((const float4*)x, A, (float*)d_out, batch);
}

// Round 3
// 23.880 us; speedup vs baseline: 1.0142x; 1.0142x over previous
//
#include <hip/hip_runtime.h>

#define NQ 4
#define DIMQ 16
#define NLAY 8
#define NOUT 4
#define NPAIR 136   // 16*17/2 upper-triangle entries
#define TPB 128     // threads per block
#define SPT 4       // samples per thread

// ---------------------------------------------------------------------------
// Single fused kernel. Each block redundantly:
//   phase 1: threads 0..63 state-vector-simulate the 4 QNN unitaries
//            (column per thread) into LDS as U[k][col][row]; thread 64
//            computes the ancilla weights w[0..4].
//   phase 2: 136 upper-triangle entries (t<=u): fold all three measurement
//            matrices at once via 8 sign-class partial sums ->
//            sA[idx] = (A0, A1, A2, 0), diag pre-halved, so
//            out[b][m] = 0.5 + sum_idx sA[idx].m * enc[t]*enc[u].
//   phase 3: each thread evaluates SPT samples against sA (float4 broadcast
//            reads, amortized over SPT samples).
// ---------------------------------------------------------------------------
__global__ __launch_bounds__(TPB) void qnn_fused(const float4* __restrict__ x,
                                                 const float* __restrict__ alpha,
                                                 const float* __restrict__ thetas,
                                                 float* __restrict__ out,
                                                 int batch, int nthreads) {
    __shared__ float U[NOUT][DIMQ][DIMQ];  // [k][col][row]
    __shared__ float w[8];                 // w[0..3]=ent0[k]^2, w[4]=tail sum
    __shared__ float4 sA[NPAIR];

    const int tid = threadIdx.x;

    // ---- phase 1: unitary simulation (64 threads) + ancilla (thread 64) ----
    if (tid < 64) {
        const int k = tid >> 4, col = tid & 15;
        float st[16];
        #pragma unroll
        for (int i = 0; i < 16; ++i) st[i] = (i == col) ? 1.0f : 0.0f;
        const float* th = thetas + k * (NLAY * NQ);
        for (int l = 0; l < NLAY; ++l) {
            for (int q = 0; q < NQ; ++q) {
                const float t = th[l * NQ + q] * 0.5f;
                const float c = cosf(t), s = sinf(t);
                const int pb = 1 << (3 - q);
                #pragma unroll
                for (int i0 = 0; i0 < 16; ++i0) {
                    if (i0 & pb) continue;
                    const int i1 = i0 | pb;
                    const float a0 = st[i0], a1 = st[i1];
                    st[i0] = c * a0 - s * a1;   // RY = [[c,-s],[s,c]]
                    st[i1] = s * a0 + c * a1;
                }
            }
            // CNOT(0,1), CNOT(1,2), CNOT(2,3): amplitude swaps
            for (int q = 0; q < NQ - 1; ++q) {
                const int cb = 1 << (3 - q), tb = 1 << (2 - q);
                #pragma unroll
                for (int i = 0; i < 16; ++i) {
                    if ((i & cb) && !(i & tb)) {
                        const int j = i | tb;
                        const float tmp = st[i]; st[i] = st[j]; st[j] = tmp;
                    }
                }
            }
        }
        #pragma unroll
        for (int r = 0; r < 16; ++r) U[k][col][r] = st[r];  // column-contig
    }
    if (tid == 64) {
        float e[8];
        #pragma unroll
        for (int i = 0; i < 8; ++i) e[i] = (i == 0) ? 1.0f : 0.0f;
        int idx = 0;
        for (int l = 0; l < 3; ++l) {
            const int p = 2 - l, pb = 1 << p;
            #pragma unroll
            for (int i0 = 0; i0 < 8; ++i0) {
                if (i0 & pb) continue;
                const int i1 = i0 | pb;
                const int blk = i0 >> (p + 1);
                const float t = alpha[idx + blk] * 0.5f;
                const float c = cosf(t), s = sinf(t);
                const float a0 = e[i0], a1 = e[i1];
                e[i0] = c * a0 - s * a1;
                e[i1] = s * a0 + c * a1;
            }
            idx += (1 << l);
        }
        for (int k = 0; k < 4; ++k) w[k] = e[k] * e[k];
        w[4] = e[4]*e[4] + e[5]*e[5] + e[6]*e[6] + e[7]*e[7];
    }
    __syncthreads();

    // ---- phase 2: fold the three matrices, m-merged ----
    for (int j = tid; j < NPAIR; j += TPB) {
        int r = j, t = 0;
        while (r >= 16 - t) { r -= 16 - t; ++t; }
        const int u = t + r;

        // gs[c] = sum_k w_k * sum_{rr: rr>>1 == c} U[k][t][rr]*U[k][u][rr]
        float gs[8] = {0,0,0,0,0,0,0,0};
        for (int k = 0; k < NOUT; ++k) {
            #pragma unroll
            for (int rr = 0; rr < 16; ++rr)
                gs[rr >> 1] = fmaf(w[k], U[k][t][rr] * U[k][u][rr], gs[rr >> 1]);
        }
        // sign of class c for m: m=0 -> bit2 of c, m=1 -> bit1, m=2 -> bit0
        float A0 = 0.f, A1 = 0.f, A2 = 0.f;
        #pragma unroll
        for (int c = 0; c < 8; ++c) {
            A0 += (c & 4) ? -gs[c] : gs[c];
            A1 += (c & 2) ? -gs[c] : gs[c];
            A2 += (c & 1) ? -gs[c] : gs[c];
        }
        float scale = 1.0f;
        if (t == u) {   // identity-block tail lives on the diagonal
            A0 += ((t >> 3) & 1) ? -w[4] : w[4];
            A1 += ((t >> 2) & 1) ? -w[4] : w[4];
            A2 += ((t >> 1) & 1) ? -w[4] : w[4];
            scale = 0.5f;  // output fold: diag x0.5, off-diag x1 (implicit x2)
        }
        sA[j] = make_float4(A0 * scale, A1 * scale, A2 * scale, 0.f);
    }
    __syncthreads();

    // ---- phase 3: SPT samples per thread ----
    const int gid = blockIdx.x * TPB + tid;
    float enc[SPT][16];
    float e0[SPT], e1[SPT], e2[SPT];
    #pragma unroll
    for (int s = 0; s < SPT; ++s) {
        const int b = gid + s * nthreads;
        const float4 xv = (b < batch) ? x[b] : make_float4(0.f, 0.f, 0.f, 0.f);
        float c0, s0, c1, s1, c2, s2, c3, s3;
        sincospif(xv.x, &s0, &c0);
        sincospif(xv.y, &s1, &c1);
        sincospif(xv.z, &s2, &c2);
        sincospif(xv.w, &s3, &c3);
        float f01[4], f23[4];
        f01[0] = c0 * c1; f01[1] = c0 * s1; f01[2] = s0 * c1; f01[3] = s0 * s1;
        f23[0] = c2 * c3; f23[1] = c2 * s3; f23[2] = s2 * c3; f23[3] = s2 * s3;
        #pragma unroll
        for (int t = 0; t < 16; ++t) enc[s][t] = f01[t >> 2] * f23[t & 3];
        e0[s] = 0.5f; e1[s] = 0.5f; e2[s] = 0.5f;
    }

    int idx = 0;
    #pragma unroll
    for (int t = 0; t < 16; ++t) {
        #pragma unroll
        for (int u = t; u < 16; ++u) {
            const float4 a = sA[idx];
            #pragma unroll
            for (int s = 0; s < SPT; ++s) {
                const float p = enc[s][t] * enc[s][u];
                e0[s] = fmaf(a.x, p, e0[s]);
                e1[s] = fmaf(a.y, p, e1[s]);
                e2[s] = fmaf(a.z, p, e2[s]);
            }
            ++idx;
        }
    }

    #pragma unroll
    for (int s = 0; s < SPT; ++s) {
        const int b = gid + s * nthreads;
        if (b < batch) {
            out[b * 3 + 0] = e0[s];
            out[b * 3 + 1] = e1[s];
            out[b * 3 + 2] = e2[s];
        }
    }
}

extern "C" void kernel_launch(void* const* d_in, const int* in_sizes, int n_in,
                              void* d_out, int out_size, void* d_ws, size_t ws_size,
                              hipStream_t stream) {
    const float* x      = (const float*)d_in[0];   // (131072, 4) f32
    const float* alpha  = (const float*)d_in[1];   // (7,) f32
    const float* thetas = (const float*)d_in[2];   // (4, 32) f32

    const int batch = in_sizes[0] / 4;
    const int blocks = (batch + TPB * SPT - 1) / (TPB * SPT);   // 256
    const int nthreads = blocks * TPB;
    qnn_fused<<<blocks, TPB, 0, stream>>>((const float4*)x, alpha, thetas,
                                          (float*)d_out, batch, nthreads);
}

// Round 4
// 14.578 us; speedup vs baseline: 1.6613x; 1.6381x over previous
//
#include <hip/hip_runtime.h>

#define NQ 4
#define DIMQ 16
#define NLAY 8
#define NOUT 4
#define NPAIR 136
#define TPB 256
#define SPT 2

// out[b][m] = 0.5 + sum_{p,q} M_m[p][q] * G01[p] * G23[q]
//   f01[i] = ((i&2)?s0:c0)*((i&1)?s1:c1), f23[j] = ((j&2)?s2:c2)*((j&1)?s3:c3)
//   G01[p] = f01[i]*f01[k] over pairs i<=k (10), G23 likewise
//   M folds the three measurement matrices A_m = sum_k w_k U_k^T D_m U_k + w4 D_m.
__global__ __launch_bounds__(TPB) void qnn_fused(const float4* __restrict__ x,
                                                 const float* __restrict__ alpha,
                                                 const float* __restrict__ thetas,
                                                 float* __restrict__ out,
                                                 int batch, int nthreads) {
    __shared__ float2 csT[128];          // (cos,sin) of thetas/2, [k*32+l*4+q]
    __shared__ float2 csA[8];            // (cos,sin) of alpha/2
    __shared__ float  U[NOUT][DIMQ][DIMQ];   // [k][col][row]
    __shared__ float  w[8];              // w[0..3]=ent0[k]^2, w[4]=tail
    __shared__ float  Af[3][DIMQ][DIMQ]; // full symmetric A_m
    __shared__ float  Mf[3][10][12];     // folded 10x10, q padded to 12

    const int tid = threadIdx.x;

    // ---- phase 0: shared angle tables ----
    if (tid < 128) {
        const float t = thetas[tid] * 0.5f;
        csT[tid] = make_float2(cosf(t), sinf(t));
    } else if (tid < 135) {
        const float t = alpha[tid - 128] * 0.5f;
        csA[tid - 128] = make_float2(cosf(t), sinf(t));
    }
    __syncthreads();

    // ---- phase 1: simulate U_k columns (threads 0..63), ancilla (thread 64) ----
    if (tid < 64) {
        const int k = tid >> 4, col = tid & 15;
        float st[16];
        #pragma unroll
        for (int i = 0; i < 16; ++i) st[i] = (i == col) ? 1.0f : 0.0f;
        #pragma unroll 1
        for (int l = 0; l < NLAY; ++l) {
            #pragma unroll
            for (int q = 0; q < NQ; ++q) {
                const float2 cs = csT[k * 32 + l * 4 + q];
                const float c = cs.x, s = cs.y;
                const int pb = 1 << (3 - q);
                #pragma unroll
                for (int i0 = 0; i0 < 16; ++i0) {
                    if (i0 & pb) continue;
                    const int i1 = i0 | pb;
                    const float a0 = st[i0], a1 = st[i1];
                    st[i0] = c * a0 - s * a1;   // RY = [[c,-s],[s,c]]
                    st[i1] = s * a0 + c * a1;
                }
            }
            #pragma unroll
            for (int q = 0; q < NQ - 1; ++q) {  // CNOT(q,q+1) amplitude swaps
                const int cb = 1 << (3 - q), tb = 1 << (2 - q);
                #pragma unroll
                for (int i = 0; i < 16; ++i) {
                    if ((i & cb) && !(i & tb)) {
                        const int j = i | tb;
                        const float tmp = st[i]; st[i] = st[j]; st[j] = tmp;
                    }
                }
            }
        }
        #pragma unroll
        for (int r = 0; r < 16; ++r) U[k][col][r] = st[r];
    }
    if (tid == 64) {
        float e[8];
        #pragma unroll
        for (int i = 0; i < 8; ++i) e[i] = (i == 0) ? 1.0f : 0.0f;
        int idx = 0;
        #pragma unroll
        for (int l = 0; l < 3; ++l) {
            const int p = 2 - l, pb = 1 << p;
            #pragma unroll
            for (int i0 = 0; i0 < 8; ++i0) {
                if (i0 & pb) continue;
                const int i1 = i0 | pb;
                const float2 cs = csA[idx + (i0 >> (p + 1))];
                const float a0 = e[i0], a1 = e[i1];
                e[i0] = cs.x * a0 - cs.y * a1;
                e[i1] = cs.y * a0 + cs.x * a1;
            }
            idx += (1 << l);
        }
        for (int k = 0; k < 4; ++k) w[k] = e[k] * e[k];
        w[4] = e[4]*e[4] + e[5]*e[5] + e[6]*e[6] + e[7]*e[7];
    }
    __syncthreads();

    // ---- phase 2a: full symmetric A_m (136 jobs) ----
    for (int j = tid; j < NPAIR; j += TPB) {
        int r = j, t = 0;
        while (r >= 16 - t) { r -= 16 - t; ++t; }
        const int u = t + r;
        float gs[8] = {0,0,0,0,0,0,0,0};
        #pragma unroll
        for (int k = 0; k < NOUT; ++k) {
            #pragma unroll
            for (int rr = 0; rr < 16; ++rr)
                gs[rr >> 1] = fmaf(w[k], U[k][t][rr] * U[k][u][rr], gs[rr >> 1]);
        }
        float A0 = 0.f, A1 = 0.f, A2 = 0.f;
        #pragma unroll
        for (int c = 0; c < 8; ++c) {
            A0 += (c & 4) ? -gs[c] : gs[c];
            A1 += (c & 2) ? -gs[c] : gs[c];
            A2 += (c & 1) ? -gs[c] : gs[c];
        }
        if (t == u) {
            A0 += ((t >> 3) & 1) ? -w[4] : w[4];
            A1 += ((t >> 2) & 1) ? -w[4] : w[4];
            A2 += ((t >> 1) & 1) ? -w[4] : w[4];
        }
        Af[0][t][u] = A0; Af[0][u][t] = A0;
        Af[1][t][u] = A1; Af[1][u][t] = A1;
        Af[2][t][u] = A2; Af[2][u][t] = A2;
    }
    __syncthreads();

    // ---- phase 2b: fold to M (360 jobs incl. zero pads); 0.5 output scale folded ----
    for (int e = tid; e < 360; e += TPB) {
        const int m = e / 120, r = e - m * 120, p = r / 12, q = r - p * 12;
        float v = 0.0f;
        if (q < 10) {
            int i, k, jj, ll;
            if (p < 4)      { i = 0; k = p; }
            else if (p < 7) { i = 1; k = p - 3; }
            else if (p < 9) { i = 2; k = p - 5; }
            else            { i = 3; k = 3; }
            if (q < 4)      { jj = 0; ll = q; }
            else if (q < 7) { jj = 1; ll = q - 3; }
            else if (q < 9) { jj = 2; ll = q - 5; }
            else            { jj = 3; ll = 3; }
            if (i < k && jj < ll)       v = Af[m][4*i+jj][4*k+ll] + Af[m][4*i+ll][4*k+jj];
            else if (i == k && jj < ll) v = Af[m][4*i+jj][4*i+ll];
            else if (i < k && jj == ll) v = Af[m][4*i+jj][4*k+jj];
            else                        v = 0.5f * Af[m][4*i+jj][4*i+jj];
        }
        Mf[m][p][q] = v;
    }
    __syncthreads();

    // ---- phase 3: SPT samples/thread ----
    const int gid = blockIdx.x * TPB + tid;
    float G01[SPT][10], G23[SPT][12], acc[SPT][3];
    #pragma unroll
    for (int s = 0; s < SPT; ++s) {
        const int b = gid + s * nthreads;
        const float4 xv = (b < batch) ? x[b] : make_float4(0.f, 0.f, 0.f, 0.f);
        float c0, s0, c1, s1, c2, s2, c3, s3;
        sincospif(xv.x, &s0, &c0);
        sincospif(xv.y, &s1, &c1);
        sincospif(xv.z, &s2, &c2);
        sincospif(xv.w, &s3, &c3);
        float f01[4], f23[4];
        f01[0] = c0 * c1; f01[1] = c0 * s1; f01[2] = s0 * c1; f01[3] = s0 * s1;
        f23[0] = c2 * c3; f23[1] = c2 * s3; f23[2] = s2 * c3; f23[3] = s2 * s3;
        int idx = 0;
        #pragma unroll
        for (int i = 0; i < 4; ++i)
            #pragma unroll
            for (int k = i; k < 4; ++k) G01[s][idx++] = f01[i] * f01[k];
        idx = 0;
        #pragma unroll
        for (int j = 0; j < 4; ++j)
            #pragma unroll
            for (int l = j; l < 4; ++l) G23[s][idx++] = f23[j] * f23[l];
        G23[s][10] = 0.f; G23[s][11] = 0.f;
        acc[s][0] = 0.5f; acc[s][1] = 0.5f; acc[s][2] = 0.5f;
    }

    #pragma unroll
    for (int m = 0; m < 3; ++m) {
        #pragma unroll
        for (int p = 0; p < 10; ++p) {
            const float4* row = (const float4*)&Mf[m][p][0];
            const float4 r0 = row[0], r1 = row[1], r2 = row[2];
            #pragma unroll
            for (int s = 0; s < SPT; ++s) {
                float z;
                z = r0.x * G23[s][0];
                z = fmaf(r0.y, G23[s][1], z);
                z = fmaf(r0.z, G23[s][2], z);
                z = fmaf(r0.w, G23[s][3], z);
                z = fmaf(r1.x, G23[s][4], z);
                z = fmaf(r1.y, G23[s][5], z);
                z = fmaf(r1.z, G23[s][6], z);
                z = fmaf(r1.w, G23[s][7], z);
                z = fmaf(r2.x, G23[s][8], z);
                z = fmaf(r2.y, G23[s][9], z);
                acc[s][m] = fmaf(G01[s][p], z, acc[s][m]);
            }
        }
    }

    #pragma unroll
    for (int s = 0; s < SPT; ++s) {
        const int b = gid + s * nthreads;
        if (b < batch) {
            out[b * 3 + 0] = acc[s][0];
            out[b * 3 + 1] = acc[s][1];
            out[b * 3 + 2] = acc[s][2];
        }
    }
}

extern "C" void kernel_launch(void* const* d_in, const int* in_sizes, int n_in,
                              void* d_out, int out_size, void* d_ws, size_t ws_size,
                              hipStream_t stream) {
    const float* x      = (const float*)d_in[0];   // (131072, 4) f32
    const float* alpha  = (const float*)d_in[1];   // (7,) f32
    const float* thetas = (const float*)d_in[2];   // (4, 32) f32

    const int batch = in_sizes[0] / 4;
    const int blocks = (batch + TPB * SPT - 1) / (TPB * SPT);   // 256
    const int nthreads = blocks * TPB;
    qnn_fused<<<blocks, TPB, 0, stream>>>((const float4*)x, alpha, thetas,
                                          (float*)d_out, batch, nthreads);
}